// Round 1
// baseline (372.505 us; speedup 1.0000x reference)
//
#include <hip/hip_runtime.h>
#include <hip/hip_bf16.h>

#define NN       100000    // nodes
#define NE       1600000   // edges
#define IN_F     256
#define HID      64
#define NC       40
#define CAP      64        // fixed CSR slots/node; P(in-deg > 64) ~ 1e-19 for Poisson(16)
#define NXCD     8         // XCDs on MI355X
#define NB_GEMM  1563      // ceil(NN/64)
#define NB_BUILD 6250      // NE/256 (NE % 256 == 0)

typedef __attribute__((ext_vector_type(8))) short bf16x8;
typedef __attribute__((ext_vector_type(4))) float f32x4;

__device__ __forceinline__ unsigned short f2bf(float x) {
    unsigned int u = __builtin_bit_cast(unsigned int, x);
    u += 0x7FFFu + ((u >> 16) & 1u);           // RNE (inputs finite)
    return (unsigned short)(u >> 16);
}
__device__ __forceinline__ float bf2f(unsigned short h) {
    unsigned int u = ((unsigned int)h) << 16;
    return __builtin_bit_cast(float, u);
}

// Real XCD id of the CU this workgroup runs on. Using the HW register (not a
// blockIdx heuristic) keeps per-XCD privatization CORRECT under any
// dispatch->XCD mapping: a counter copy is only ever touched from one XCD,
// so workgroup-scope (local-L2) atomics on it are globally correct sums.
__device__ __forceinline__ int xcc_id() {
    int x;
    asm("s_getreg_b32 %0, hwreg(HW_REG_XCC_ID)" : "=s"(x));
    return x & (NXCD - 1);
}

// ---------------- W1 -> bf16 B-fragment pre-pack ----------------
// Bp[((kt*4+nt)*64 + lane)*8 + j] = bf16(W1[kt*32 + (lane>>4)*8 + j][nt*16 + (lane&15)])
__global__ __launch_bounds__(256) void k_packW1(const float* __restrict__ W1,
                                                unsigned short* __restrict__ Bp) {
    int tid = blockIdx.x * 256 + threadIdx.x;
    if (tid >= 8 * 4 * 64) return;
    const int lane = tid & 63, nt = (tid >> 6) & 3, kt = tid >> 8;
    const int col = nt * 16 + (lane & 15);
    const int kb  = kt * 32 + (lane >> 4) * 8;
    unsigned short o[8];
    #pragma unroll
    for (int j = 0; j < 8; ++j) o[j] = f2bf(W1[(kb + j) * HID + col]);
    #pragma unroll
    for (int j = 0; j < 8; ++j) Bp[tid * 8 + j] = o[j];
}

// ---------------- fused: GEMM1 (MFMA, bf16 out, unscaled) + CSR build ----------
// blocks [0, NB_GEMM): h1b[r][c] = bf16( sum_k X[r][k]*W1[k][c] )   (nsrc deferred)
// blocks [NB_GEMM, NB_GEMM+NB_BUILD): degree histograms + padded-CSR placement.
// Theory r1: build was bound by memory-side device-atomic throughput
// (~16 G/s: 3.2M atomics ~= 196us). odeg needs no return value -> privatize
// per-XCD and use workgroup-scope (local-L2) atomics, halving memory-side
// atomic count. ideg keeps agent scope (its return assigns the CSR slot).
__global__ __launch_bounds__(256) void k_fused(const float* __restrict__ X,
                                               const unsigned short* __restrict__ Bp,
                                               const int* __restrict__ src,
                                               const int* __restrict__ dst,
                                               int* __restrict__ odeg8,
                                               int* __restrict__ ideg,
                                               int* __restrict__ eidx,
                                               unsigned short* __restrict__ h1b) {
    if (blockIdx.x >= NB_GEMM) {
        // ---------- build ----------
        const int e = (blockIdx.x - NB_GEMM) * 256 + threadIdx.x;   // < NE exactly
        const int s = src[e], d = dst[e];
        const int xc = xcc_id();
        __hip_atomic_fetch_add(&odeg8[(size_t)xc * NN + s], 1,
                               __ATOMIC_RELAXED, __HIP_MEMORY_SCOPE_WORKGROUP);
        const int c = atomicAdd(&ideg[d], 1);
        if (c < CAP) eidx[d * CAP + c] = s;
        return;
    }
    // ---------- gemm1 ----------
    const int lane = threadIdx.x & 63;
    const int wid  = threadIdx.x >> 6;
    const int r0w  = blockIdx.x * 64 + wid * 16;
    if (r0w >= NN) return;
    const int r  = r0w + (lane & 15);
    const int rc = (r < NN) ? r : (NN - 1);
    const float* xrow = X + (size_t)rc * IN_F + (lane >> 4) * 8;
    const bf16x8* bp  = reinterpret_cast<const bf16x8*>(Bp) + lane;

    f32x4 acc0 = {0.f, 0.f, 0.f, 0.f};
    f32x4 acc1 = {0.f, 0.f, 0.f, 0.f};
    f32x4 acc2 = {0.f, 0.f, 0.f, 0.f};
    f32x4 acc3 = {0.f, 0.f, 0.f, 0.f};

    #pragma unroll
    for (int kt = 0; kt < 8; ++kt) {
        const f32x4 v0 = *reinterpret_cast<const f32x4*>(xrow + kt * 32);
        const f32x4 v1 = *reinterpret_cast<const f32x4*>(xrow + kt * 32 + 4);
        bf16x8 a;
        a[0] = (short)f2bf(v0[0]);
        a[1] = (short)f2bf(v0[1]);
        a[2] = (short)f2bf(v0[2]);
        a[3] = (short)f2bf(v0[3]);
        a[4] = (short)f2bf(v1[0]);
        a[5] = (short)f2bf(v1[1]);
        a[6] = (short)f2bf(v1[2]);
        a[7] = (short)f2bf(v1[3]);
        const bf16x8 b0 = bp[(kt * 4 + 0) * 64];
        const bf16x8 b1 = bp[(kt * 4 + 1) * 64];
        const bf16x8 b2 = bp[(kt * 4 + 2) * 64];
        const bf16x8 b3 = bp[(kt * 4 + 3) * 64];
        acc0 = __builtin_amdgcn_mfma_f32_16x16x32_bf16(a, b0, acc0, 0, 0, 0);
        acc1 = __builtin_amdgcn_mfma_f32_16x16x32_bf16(a, b1, acc1, 0, 0, 0);
        acc2 = __builtin_amdgcn_mfma_f32_16x16x32_bf16(a, b2, acc2, 0, 0, 0);
        acc3 = __builtin_amdgcn_mfma_f32_16x16x32_bf16(a, b3, acc3, 0, 0, 0);
    }

    // C/D layout: col = lane&15, row = (lane>>4)*4 + reg   [m89-verified]
    const int crow = r0w + (lane >> 4) * 4;
    const int ccol = lane & 15;
    #pragma unroll
    for (int rr = 0; rr < 4; ++rr) {
        const int orow = crow + rr;
        if (orow < NN) {
            unsigned short* o = h1b + (size_t)orow * HID + ccol;
            o[0]  = f2bf(acc0[rr]);
            o[16] = f2bf(acc1[rr]);
            o[32] = f2bf(acc2[rr]);
            o[48] = f2bf(acc3[rr]);
        }
    }
}

// ---------------- merge odeg copies + pre-scale h1b rows by norm_src ---------
// 16-lane group per node: lanes 0-7 sum the 8 XCD-private counters, all 16
// lanes rescale the 128B h1b row in place. Moves the per-edge odeg gather +
// rsqrt out of k_agg64 (1.6M scattered 4B loads -> 100K row passes).
__global__ __launch_bounds__(256) void k_scale(const int* __restrict__ odeg8,
                                               unsigned short* __restrict__ h1b,
                                               float* __restrict__ nsrcf) {
    const int gw = (blockIdx.x * 256 + threadIdx.x) >> 4;   // node
    const int gl = threadIdx.x & 15;                        // lane in group
    if (gw >= NN) return;
    int v = 0;
    if (gl < 8) v = odeg8[(size_t)gl * NN + gw];
    v += __shfl_xor(v, 4);
    v += __shfl_xor(v, 2);
    v += __shfl_xor(v, 1);
    const int base = (int)(threadIdx.x & 63) & ~15;         // group base lane
    const float ns = rsqrtf(fmaxf((float)__shfl(v, base), 1.f));
    if (gl == 0) nsrcf[gw] = ns;
    uint2* row = reinterpret_cast<uint2*>(h1b + (size_t)gw * HID);
    uint2 u = row[gl];
    const unsigned short a0 = (unsigned short)(u.x & 0xffffu);
    const unsigned short a1 = (unsigned short)(u.x >> 16);
    const unsigned short a2 = (unsigned short)(u.y & 0xffffu);
    const unsigned short a3 = (unsigned short)(u.y >> 16);
    u.x = (unsigned)f2bf(bf2f(a0) * ns) | ((unsigned)f2bf(bf2f(a1) * ns) << 16);
    u.y = (unsigned)f2bf(bf2f(a2) * ns) | ((unsigned)f2bf(bf2f(a3) * ns) << 16);
    row[gl] = u;
}

// ---------------- aggregation, 64 feats: hout = ndst*(sum h1_scaled) + b1 ----
// one wave per dst node; lane = feature; h1b already carries nsrc
__global__ __launch_bounds__(256) void k_agg64(const int* __restrict__ eidx,
                                               const int* __restrict__ ideg,
                                               const unsigned short* __restrict__ h1b,
                                               const float* __restrict__ b1,
                                               float* __restrict__ hout) {
    const int w    = (blockIdx.x * 256 + threadIdx.x) >> 6;
    const int lane = threadIdx.x & 63;
    if (w >= NN) return;
    const int cnt = ideg[w];
    const int m   = cnt < CAP ? cnt : CAP;
    const int* row = eidx + w * CAP;                       // 256B-aligned
    float acc = 0.f;
    int j = 0;
    for (; j + 4 <= m; j += 4) {
        const int4 q = *reinterpret_cast<const int4*>(row + j);
        const float v0 = bf2f(h1b[(size_t)q.x * HID + lane]);
        const float v1 = bf2f(h1b[(size_t)q.y * HID + lane]);
        const float v2 = bf2f(h1b[(size_t)q.z * HID + lane]);
        const float v3 = bf2f(h1b[(size_t)q.w * HID + lane]);
        acc += (v0 + v1) + (v2 + v3);
    }
    for (; j < m; ++j)
        acc += bf2f(h1b[(size_t)row[j] * HID + lane]);
    const float nd = rsqrtf(fmaxf((float)cnt, 1.f));
    hout[(size_t)w * HID + lane] = fmaf(acc, nd, b1[lane]);
}

// ---------------- layer 2 GEMM: xwb[n][c] = bf16( (relu(h[n]) @ W2)[c] * nsrc[n] )
__global__ __launch_bounds__(256) void k_gemm2(const float* __restrict__ h,
                                               const float* __restrict__ W2,
                                               const float* __restrict__ nsrcf,
                                               unsigned short* __restrict__ xwb) {
    __shared__ float lw[HID * NC];                 // 10 KiB
    for (int i = threadIdx.x; i < HID * NC; i += 256) lw[i] = W2[i];
    __syncthreads();
    int idx = blockIdx.x * 256 + threadIdx.x;
    if (idx >= NN * NC) return;
    int nrow = idx / NC, c = idx - nrow * NC;
    const float4* hr = reinterpret_cast<const float4*>(h + (size_t)nrow * HID);
    float acc = 0.f;
    #pragma unroll
    for (int k4 = 0; k4 < HID / 4; ++k4) {
        float4 v = hr[k4];
        int k = k4 * 4;
        acc = fmaf(fmaxf(v.x, 0.f), lw[(k + 0) * NC + c], acc);
        acc = fmaf(fmaxf(v.y, 0.f), lw[(k + 1) * NC + c], acc);
        acc = fmaf(fmaxf(v.z, 0.f), lw[(k + 2) * NC + c], acc);
        acc = fmaf(fmaxf(v.w, 0.f), lw[(k + 3) * NC + c], acc);
    }
    xwb[idx] = f2bf(acc * nsrcf[nrow]);
}

// ---------------- aggregation, 40 feats: out = ndst*(sum xwb) + b2 -----------
__global__ __launch_bounds__(256) void k_agg40(const int* __restrict__ eidx,
                                               const int* __restrict__ ideg,
                                               const unsigned short* __restrict__ xwb,
                                               const float* __restrict__ b2,
                                               float* __restrict__ out) {
    const int w    = (blockIdx.x * 256 + threadIdx.x) >> 6;
    const int lane = threadIdx.x & 63;
    if (w >= NN || lane >= NC) return;
    const int cnt = ideg[w];
    const int m   = cnt < CAP ? cnt : CAP;
    const int* row = eidx + w * CAP;
    float acc = 0.f;
    int j = 0;
    for (; j + 4 <= m; j += 4) {
        const int4 q = *reinterpret_cast<const int4*>(row + j);
        const float v0 = bf2f(xwb[(size_t)q.x * NC + lane]);
        const float v1 = bf2f(xwb[(size_t)q.y * NC + lane]);
        const float v2 = bf2f(xwb[(size_t)q.z * NC + lane]);
        const float v3 = bf2f(xwb[(size_t)q.w * NC + lane]);
        acc += (v0 + v1) + (v2 + v3);
    }
    for (; j < m; ++j) acc += bf2f(xwb[(size_t)row[j] * NC + lane]);
    const float nd = rsqrtf(fmaxf((float)cnt, 1.f));
    out[(size_t)w * NC + lane] = fmaf(acc, nd, b2[lane]);
}

extern "C" void kernel_launch(void* const* d_in, const int* in_sizes, int n_in,
                              void* d_out, int out_size, void* d_ws, size_t ws_size,
                              hipStream_t stream) {
    const float* X   = (const float*)d_in[0];
    const int*   src = (const int*)d_in[1];
    const int*   dst = (const int*)d_in[2];
    const float* W1  = (const float*)d_in[3];
    const float* b1  = (const float*)d_in[4];
    const float* W2  = (const float*)d_in[5];
    const float* b2  = (const float*)d_in[6];

    float* out  = (float*)d_out;
    float* xout = out;                          // [NN*NC] final layer-2 output
    float* hout = out + (size_t)NN * NC;        // [NN*HID] layer-1 output h

    // ---- workspace layout (16B-aligned pieces) ----
    char* ws = (char*)d_ws;
    int* ideg  = (int*)ws;                            ws += sizeof(int) * NN;            // 400000 B
    int* odeg8 = (int*)ws;                            ws += sizeof(int) * (size_t)NXCD * NN;  // 3.2 MB
    int* eidx  = (int*)ws;                            ws += sizeof(int) * (size_t)NN * CAP;   // 25.6 MB
    unsigned short* Bp  = (unsigned short*)ws;        ws += sizeof(unsigned short) * 8 * 4 * 64 * 8;
    float* nsrcf = (float*)ws;                        ws += sizeof(float) * NN;          // 400000 B
    unsigned short* h1b = (unsigned short*)ws;        // [NN*HID] bf16, 12.8 MB
    unsigned short* xwb = h1b;                        // reuse: h1b dead after agg64

    hipMemsetAsync(ideg, 0, sizeof(int) * (size_t)(NXCD + 1) * NN, stream);  // ideg+odeg8 contiguous
    k_packW1<<<8, 256, 0, stream>>>(W1, Bp);
    k_fused <<<NB_GEMM + NB_BUILD, 256, 0, stream>>>(X, Bp, src, dst, odeg8, ideg, eidx, h1b);
    k_scale <<<(NN * 16 + 255) / 256, 256, 0, stream>>>(odeg8, h1b, nsrcf);
    k_agg64 <<<(NN * 64 + 255) / 256, 256, 0, stream>>>(eidx, ideg, h1b, b1, hout);
    k_gemm2 <<<(NN * NC + 255) / 256, 256, 0, stream>>>(hout, W2, nsrcf, xwb);
    k_agg40 <<<(NN * 64 + 255) / 256, 256, 0, stream>>>(eidx, ideg, xwb, b2, xout);
}

// Round 2
// 319.398 us; speedup vs baseline: 1.1663x; 1.1663x over previous
//
#include <hip/hip_runtime.h>
#include <hip/hip_bf16.h>

#define NN       100000    // nodes
#define NE       1600000   // edges
#define IN_F     256
#define HID      64
#define NC       40
#define CAP      64        // fixed CSR slots/node; P(in-deg > 64) ~ 1e-19 for Poisson(16)
#define NBKT     391       // dst buckets: bucket = d >> 8 (256 nodes each)
#define NBP1     256       // partition blocks; EPB edges each
#define EPB      6250      // NE / NBP1 (exact)
#define ODCH     16        // odeg chunks (6250 bins each; 16*6250 == NN exactly)
#define ODPART   8         // odeg partial histograms (merged by k_scale)
#define ODEPS    200000    // NE / ODPART edges per slice (exact)
#define NB_GEMM  1563      // ceil(NN/64)

typedef __attribute__((ext_vector_type(8))) short bf16x8;
typedef __attribute__((ext_vector_type(4))) float f32x4;

__device__ __forceinline__ unsigned short f2bf(float x) {
    unsigned int u = __builtin_bit_cast(unsigned int, x);
    u += 0x7FFFu + ((u >> 16) & 1u);           // RNE (inputs finite)
    return (unsigned short)(u >> 16);
}
__device__ __forceinline__ float bf2f(unsigned short h) {
    unsigned int u = ((unsigned int)h) << 16;
    return __builtin_bit_cast(float, u);
}

// ---------------- W1 -> bf16 B-fragment pre-pack ----------------
__global__ __launch_bounds__(256) void k_packW1(const float* __restrict__ W1,
                                                unsigned short* __restrict__ Bp) {
    int tid = blockIdx.x * 256 + threadIdx.x;
    if (tid >= 8 * 4 * 64) return;
    const int lane = tid & 63, nt = (tid >> 6) & 3, kt = tid >> 8;
    const int col = nt * 16 + (lane & 15);
    const int kb  = kt * 32 + (lane >> 4) * 8;
    unsigned short o[8];
    #pragma unroll
    for (int j = 0; j < 8; ++j) o[j] = f2bf(W1[(kb + j) * HID + col]);
    #pragma unroll
    for (int j = 0; j < 8; ++j) Bp[tid * 8 + j] = o[j];
}

// ---------------- fused: GEMM1 (MFMA) | dst bucket-count | odeg chunk-histo ----
// r2 theory: the old build was bound by memory-side scattered-op throughput
// (2 global atomics + 1 scattered 4B store per edge ~= 27G ops/s ceiling;
// WRITE_SIZE showed ~102MB of partial-line writeback from eidx scatter).
// Replace with a counting sort: ZERO global atomics, LDS atomics only,
// dense / segment-local global writes.
__global__ __launch_bounds__(256) void k_fused1(const float* __restrict__ X,
                                                const unsigned short* __restrict__ Bp,
                                                const int* __restrict__ src,
                                                const int* __restrict__ dst,
                                                unsigned short* __restrict__ h1b,
                                                int* __restrict__ gcnt,
                                                int* __restrict__ odeg8) {
    __shared__ int sh[6250];                  // 25000 B (odeg chunk); count uses first 391
    const int bid = blockIdx.x, t = threadIdx.x;

    if (bid >= NB_GEMM + NBP1) {
        // ---------- odeg: chunked-LDS streaming histogram ----------
        const int id = bid - NB_GEMM - NBP1;          // [0, ODCH*ODPART)
        const int p  = id & (ODPART - 1);             // edge slice
        const int c  = id >> 3;                       // bin chunk [0,16)
        for (int j = t; j < 6250; j += 256) sh[j] = 0;
        __syncthreads();
        const int lo = c * 6250, hi = lo + 6250;
        const int4* s4 = reinterpret_cast<const int4*>(src) + p * (ODEPS / 4);
        for (int i = t; i < ODEPS / 4; i += 256) {
            const int4 v = s4[i];
            if (v.x >= lo && v.x < hi) atomicAdd(&sh[v.x - lo], 1);
            if (v.y >= lo && v.y < hi) atomicAdd(&sh[v.y - lo], 1);
            if (v.z >= lo && v.z < hi) atomicAdd(&sh[v.z - lo], 1);
            if (v.w >= lo && v.w < hi) atomicAdd(&sh[v.w - lo], 1);
        }
        __syncthreads();
        for (int j = t; j < 6250; j += 256) odeg8[(size_t)p * NN + lo + j] = sh[j];
        return;
    }
    if (bid >= NB_GEMM) {
        // ---------- partition pass a: per-(block,bucket) dst counts ----------
        const int cb = bid - NB_GEMM;                 // [0, NBP1)
        for (int j = t; j < NBKT; j += 256) sh[j] = 0;
        __syncthreads();
        const int e0 = cb * EPB;
        for (int i = t; i < EPB; i += 256) atomicAdd(&sh[dst[e0 + i] >> 8], 1);
        __syncthreads();
        for (int k = t; k < NBKT; k += 256) gcnt[k * NBP1 + cb] = sh[k];
        return;
    }
    // ---------- gemm1 (unchanged) ----------
    const int lane = t & 63;
    const int wid  = t >> 6;
    const int r0w  = bid * 64 + wid * 16;
    if (r0w >= NN) return;
    const int r  = r0w + (lane & 15);
    const int rc = (r < NN) ? r : (NN - 1);
    const float* xrow = X + (size_t)rc * IN_F + (lane >> 4) * 8;
    const bf16x8* bp  = reinterpret_cast<const bf16x8*>(Bp) + lane;

    f32x4 acc0 = {0.f, 0.f, 0.f, 0.f};
    f32x4 acc1 = {0.f, 0.f, 0.f, 0.f};
    f32x4 acc2 = {0.f, 0.f, 0.f, 0.f};
    f32x4 acc3 = {0.f, 0.f, 0.f, 0.f};

    #pragma unroll
    for (int kt = 0; kt < 8; ++kt) {
        const f32x4 v0 = *reinterpret_cast<const f32x4*>(xrow + kt * 32);
        const f32x4 v1 = *reinterpret_cast<const f32x4*>(xrow + kt * 32 + 4);
        bf16x8 a;
        a[0] = (short)f2bf(v0[0]);
        a[1] = (short)f2bf(v0[1]);
        a[2] = (short)f2bf(v0[2]);
        a[3] = (short)f2bf(v0[3]);
        a[4] = (short)f2bf(v1[0]);
        a[5] = (short)f2bf(v1[1]);
        a[6] = (short)f2bf(v1[2]);
        a[7] = (short)f2bf(v1[3]);
        const bf16x8 b0 = bp[(kt * 4 + 0) * 64];
        const bf16x8 b1 = bp[(kt * 4 + 1) * 64];
        const bf16x8 b2 = bp[(kt * 4 + 2) * 64];
        const bf16x8 b3 = bp[(kt * 4 + 3) * 64];
        acc0 = __builtin_amdgcn_mfma_f32_16x16x32_bf16(a, b0, acc0, 0, 0, 0);
        acc1 = __builtin_amdgcn_mfma_f32_16x16x32_bf16(a, b1, acc1, 0, 0, 0);
        acc2 = __builtin_amdgcn_mfma_f32_16x16x32_bf16(a, b2, acc2, 0, 0, 0);
        acc3 = __builtin_amdgcn_mfma_f32_16x16x32_bf16(a, b3, acc3, 0, 0, 0);
    }

    // C/D layout: col = lane&15, row = (lane>>4)*4 + reg   [m89-verified]
    const int crow = r0w + (lane >> 4) * 4;
    const int ccol = lane & 15;
    #pragma unroll
    for (int rr = 0; rr < 4; ++rr) {
        const int orow = crow + rr;
        if (orow < NN) {
            unsigned short* o = h1b + (size_t)orow * HID + ccol;
            o[0]  = f2bf(acc0[rr]);
            o[16] = f2bf(acc1[rr]);
            o[32] = f2bf(acc2[rr]);
            o[48] = f2bf(acc3[rr]);
        }
    }
}

// ---------------- scan A: per-bucket total = sum over blocks ----------------
__global__ __launch_bounds__(256) void k_scanA(const int* __restrict__ gcnt,
                                               int* __restrict__ bsum) {
    __shared__ int red[256];
    const int k = blockIdx.x, t = threadIdx.x;
    red[t] = gcnt[k * NBP1 + t];              // NBP1 == 256
    __syncthreads();
    for (int off = 128; off > 0; off >>= 1) {
        if (t < off) red[t] += red[t + off];
        __syncthreads();
    }
    if (t == 0) bsum[k] = red[0];
}

// ---------------- scan B: exclusive scan of bucket totals -> bstart[0..NBKT] --
__global__ __launch_bounds__(512) void k_scanB(const int* __restrict__ bsum,
                                               int* __restrict__ bstart) {
    __shared__ int sa[512], sb[512];
    const int t = threadIdx.x;
    const int x = (t < NBKT) ? bsum[t] : 0;
    sa[t] = x;
    __syncthreads();
    int* pin = sa; int* pout = sb;
    for (int off = 1; off < 512; off <<= 1) {
        int v = pin[t];
        if (t >= off) v += pin[t - off];
        pout[t] = v;
        __syncthreads();
        int* tmp = pin; pin = pout; pout = tmp;
    }
    if (t <= NBKT) bstart[t] = pin[t] - x;    // exclusive; bstart[NBKT] == NE
}

// ---------------- scan C: per-bucket row exclusive scan -> segment bases ------
// in-place: gcnt[k][b] becomes gbase[k][b] = bstart[k] + sum_{b'<b} gcnt[k][b']
__global__ __launch_bounds__(256) void k_scanC(int* __restrict__ gcnt,
                                               const int* __restrict__ bstart) {
    __shared__ int sa[256], sb[256];
    const int k = blockIdx.x, t = threadIdx.x;
    const int x = gcnt[k * NBP1 + t];
    sa[t] = x;
    __syncthreads();
    int* pin = sa; int* pout = sb;
    for (int off = 1; off < 256; off <<= 1) {
        int v = pin[t];
        if (t >= off) v += pin[t - off];
        pout[t] = v;
        __syncthreads();
        int* tmp = pin; pin = pout; pout = tmp;
    }
    gcnt[k * NBP1 + t] = bstart[k] + pin[t] - x;
}

// ---------------- partition pass b: scatter edges into bucket segments --------
// pedge[pos] = src | (d&255)<<17  (src < 2^17). Writes land in ~16-edge
// contiguous per-(block,bucket) segments -> near-full-line write granularity.
__global__ __launch_bounds__(256) void k_scatter(const int* __restrict__ src,
                                                 const int* __restrict__ dst,
                                                 const int* __restrict__ gbase,
                                                 int* __restrict__ pedge) {
    __shared__ int cur[NBKT];
    const int b = blockIdx.x, t = threadIdx.x;
    for (int k = t; k < NBKT; k += 256) cur[k] = gbase[k * NBP1 + b];
    __syncthreads();
    const int e0 = b * EPB;
    for (int i = t; i < EPB; i += 256) {
        const int d = dst[e0 + i], s = src[e0 + i];
        const int pos = atomicAdd(&cur[d >> 8], 1);   // LDS atomic
        pedge[pos] = s | ((d & 255) << 17);
    }
}

// ---------------- place: per-bucket CSR slot assignment (LDS counters) --------
// block k owns dst range [k*256, k*256+256): reads its CONTIGUOUS edge range,
// writes eidx into its private 64KB region (single-XCD, full-line writebacks),
// writes ideg densely. Zero global atomics.
__global__ __launch_bounds__(256) void k_place(const int* __restrict__ pedge,
                                               const int* __restrict__ bstart,
                                               int* __restrict__ eidx,
                                               int* __restrict__ ideg) {
    __shared__ int cnt[256];
    const int k = blockIdx.x, t = threadIdx.x;
    cnt[t] = 0;
    __syncthreads();
    const int i0 = bstart[k], i1 = bstart[k + 1];
    for (int i = i0 + t; i < i1; i += 256) {
        const int v  = pedge[i];
        const int s  = v & 0x1FFFF;
        const int lo = v >> 17;
        const int c  = atomicAdd(&cnt[lo], 1);        // LDS atomic
        if (c < CAP) eidx[(size_t)((k << 8) | lo) * CAP + c] = s;
    }
    __syncthreads();
    const int d = (k << 8) | t;
    if (d < NN) ideg[d] = cnt[t];
}

// ---------------- merge odeg partials + pre-scale h1b rows by norm_src -------
__global__ __launch_bounds__(256) void k_scale(const int* __restrict__ odeg8,
                                               unsigned short* __restrict__ h1b,
                                               float* __restrict__ nsrcf) {
    const int gw = (blockIdx.x * 256 + threadIdx.x) >> 4;   // node
    const int gl = threadIdx.x & 15;                        // lane in group
    if (gw >= NN) return;
    int v = 0;
    if (gl < 8) v = odeg8[(size_t)gl * NN + gw];
    v += __shfl_xor(v, 4);
    v += __shfl_xor(v, 2);
    v += __shfl_xor(v, 1);
    const int base = (int)(threadIdx.x & 63) & ~15;         // group base lane
    const float ns = rsqrtf(fmaxf((float)__shfl(v, base), 1.f));
    if (gl == 0) nsrcf[gw] = ns;
    uint2* row = reinterpret_cast<uint2*>(h1b + (size_t)gw * HID);
    uint2 u = row[gl];
    const unsigned short a0 = (unsigned short)(u.x & 0xffffu);
    const unsigned short a1 = (unsigned short)(u.x >> 16);
    const unsigned short a2 = (unsigned short)(u.y & 0xffffu);
    const unsigned short a3 = (unsigned short)(u.y >> 16);
    u.x = (unsigned)f2bf(bf2f(a0) * ns) | ((unsigned)f2bf(bf2f(a1) * ns) << 16);
    u.y = (unsigned)f2bf(bf2f(a2) * ns) | ((unsigned)f2bf(bf2f(a3) * ns) << 16);
    row[gl] = u;
}

// ---------------- aggregation, 64 feats: hout = ndst*(sum h1_scaled) + b1 ----
__global__ __launch_bounds__(256) void k_agg64(const int* __restrict__ eidx,
                                               const int* __restrict__ ideg,
                                               const unsigned short* __restrict__ h1b,
                                               const float* __restrict__ b1,
                                               float* __restrict__ hout) {
    const int w    = (blockIdx.x * 256 + threadIdx.x) >> 6;
    const int lane = threadIdx.x & 63;
    if (w >= NN) return;
    const int cnt = ideg[w];
    const int m   = cnt < CAP ? cnt : CAP;
    const int* row = eidx + w * CAP;                       // 256B-aligned
    float acc = 0.f;
    int j = 0;
    for (; j + 4 <= m; j += 4) {
        const int4 q = *reinterpret_cast<const int4*>(row + j);
        const float v0 = bf2f(h1b[(size_t)q.x * HID + lane]);
        const float v1 = bf2f(h1b[(size_t)q.y * HID + lane]);
        const float v2 = bf2f(h1b[(size_t)q.z * HID + lane]);
        const float v3 = bf2f(h1b[(size_t)q.w * HID + lane]);
        acc += (v0 + v1) + (v2 + v3);
    }
    for (; j < m; ++j)
        acc += bf2f(h1b[(size_t)row[j] * HID + lane]);
    const float nd = rsqrtf(fmaxf((float)cnt, 1.f));
    hout[(size_t)w * HID + lane] = fmaf(acc, nd, b1[lane]);
}

// ---------------- layer 2 GEMM: xwb[n][c] = bf16( (relu(h[n]) @ W2)[c] * nsrc[n] )
__global__ __launch_bounds__(256) void k_gemm2(const float* __restrict__ h,
                                               const float* __restrict__ W2,
                                               const float* __restrict__ nsrcf,
                                               unsigned short* __restrict__ xwb) {
    __shared__ float lw[HID * NC];                 // 10 KiB
    for (int i = threadIdx.x; i < HID * NC; i += 256) lw[i] = W2[i];
    __syncthreads();
    int idx = blockIdx.x * 256 + threadIdx.x;
    if (idx >= NN * NC) return;
    int nrow = idx / NC, c = idx - nrow * NC;
    const float4* hr = reinterpret_cast<const float4*>(h + (size_t)nrow * HID);
    float acc = 0.f;
    #pragma unroll
    for (int k4 = 0; k4 < HID / 4; ++k4) {
        float4 v = hr[k4];
        int k = k4 * 4;
        acc = fmaf(fmaxf(v.x, 0.f), lw[(k + 0) * NC + c], acc);
        acc = fmaf(fmaxf(v.y, 0.f), lw[(k + 1) * NC + c], acc);
        acc = fmaf(fmaxf(v.z, 0.f), lw[(k + 2) * NC + c], acc);
        acc = fmaf(fmaxf(v.w, 0.f), lw[(k + 3) * NC + c], acc);
    }
    xwb[idx] = f2bf(acc * nsrcf[nrow]);
}

// ---------------- aggregation, 40 feats: out = ndst*(sum xwb) + b2 -----------
__global__ __launch_bounds__(256) void k_agg40(const int* __restrict__ eidx,
                                               const int* __restrict__ ideg,
                                               const unsigned short* __restrict__ xwb,
                                               const float* __restrict__ b2,
                                               float* __restrict__ out) {
    const int w    = (blockIdx.x * 256 + threadIdx.x) >> 6;
    const int lane = threadIdx.x & 63;
    if (w >= NN || lane >= NC) return;
    const int cnt = ideg[w];
    const int m   = cnt < CAP ? cnt : CAP;
    const int* row = eidx + w * CAP;
    float acc = 0.f;
    int j = 0;
    for (; j + 4 <= m; j += 4) {
        const int4 q = *reinterpret_cast<const int4*>(row + j);
        const float v0 = bf2f(xwb[(size_t)q.x * NC + lane]);
        const float v1 = bf2f(xwb[(size_t)q.y * NC + lane]);
        const float v2 = bf2f(xwb[(size_t)q.z * NC + lane]);
        const float v3 = bf2f(xwb[(size_t)q.w * NC + lane]);
        acc += (v0 + v1) + (v2 + v3);
    }
    for (; j < m; ++j) acc += bf2f(xwb[(size_t)row[j] * NC + lane]);
    const float nd = rsqrtf(fmaxf((float)cnt, 1.f));
    out[(size_t)w * NC + lane] = fmaf(acc, nd, b2[lane]);
}

extern "C" void kernel_launch(void* const* d_in, const int* in_sizes, int n_in,
                              void* d_out, int out_size, void* d_ws, size_t ws_size,
                              hipStream_t stream) {
    const float* X   = (const float*)d_in[0];
    const int*   src = (const int*)d_in[1];
    const int*   dst = (const int*)d_in[2];
    const float* W1  = (const float*)d_in[3];
    const float* b1  = (const float*)d_in[4];
    const float* W2  = (const float*)d_in[5];
    const float* b2  = (const float*)d_in[6];

    float* out  = (float*)d_out;
    float* xout = out;                          // [NN*NC] final layer-2 output
    float* hout = out + (size_t)NN * NC;        // [NN*HID] layer-1 output h

    // ---- scratch living in d_out (liveness-checked):
    // gcnt/bsum/bstart in xout region: dead before k_agg40 writes xout.
    // pedge in hout region: dead before k_agg64 writes hout.
    int* gcnt   = (int*)xout;                   // [NBKT*NBP1] counts -> bases (in-place)
    int* bsum   = gcnt + NBKT * NBP1;           // [NBKT]
    int* bstart = bsum + 392;                   // [NBKT+1]
    int* pedge  = (int*)hout;                   // [NE] packed (src | dlow<<17)

    // ---- workspace layout (identical footprint to the proven r0 layout) ----
    char* ws = (char*)d_ws;
    int* ideg  = (int*)ws;                            ws += sizeof(int) * NN;
    int* odeg8 = (int*)ws;                            ws += sizeof(int) * (size_t)ODPART * NN;
    int* eidx  = (int*)ws;                            ws += sizeof(int) * (size_t)NN * CAP;
    unsigned short* Bp  = (unsigned short*)ws;        ws += sizeof(unsigned short) * 8 * 4 * 64 * 8;
    float* nsrcf = (float*)ws;                        ws += sizeof(float) * NN;
    unsigned short* h1b = (unsigned short*)ws;        // [NN*HID] bf16, 12.8 MB
    unsigned short* xwb = h1b;                        // reuse: h1b dead after agg64

    // no memsets needed: every consumed buffer is fully written each launch
    k_packW1 <<<8, 256, 0, stream>>>(W1, Bp);
    k_fused1 <<<NB_GEMM + NBP1 + ODCH * ODPART, 256, 0, stream>>>(X, Bp, src, dst,
                                                                  h1b, gcnt, odeg8);
    k_scanA  <<<NBKT, 256, 0, stream>>>(gcnt, bsum);
    k_scanB  <<<1, 512, 0, stream>>>(bsum, bstart);
    k_scanC  <<<NBKT, 256, 0, stream>>>(gcnt, bstart);
    k_scatter<<<NBP1, 256, 0, stream>>>(src, dst, gcnt, pedge);
    k_place  <<<NBKT, 256, 0, stream>>>(pedge, bstart, eidx, ideg);
    k_scale  <<<(NN * 16 + 255) / 256, 256, 0, stream>>>(odeg8, h1b, nsrcf);
    k_agg64  <<<(NN * 64 + 255) / 256, 256, 0, stream>>>(eidx, ideg, h1b, b1, hout);
    k_gemm2  <<<(NN * NC + 255) / 256, 256, 0, stream>>>(hout, W2, nsrcf, xwb);
    k_agg40  <<<(NN * 64 + 255) / 256, 256, 0, stream>>>(eidx, ideg, xwb, b2, xout);
}

// Round 3
// 272.877 us; speedup vs baseline: 1.3651x; 1.1705x over previous
//
#include <hip/hip_runtime.h>
#include <hip/hip_bf16.h>

#define NN       100000    // nodes
#define NE       1600000   // edges
#define IN_F     256
#define HID      64
#define NC       40
#define CAP      64        // fixed CSR slots/node; P(in-deg > 64) ~ 1e-19 for Poisson(16)
#define NBKT     391       // node buckets: bucket = id >> 8 (256 nodes each)
#define NBP1     256       // partition blocks; EPB edges each
#define EPB      6250      // NE / NBP1 (exact)
#define NB_GEMM  1563      // ceil(NN/64)

typedef __attribute__((ext_vector_type(8))) short bf16x8;
typedef __attribute__((ext_vector_type(4))) float f32x4;

__device__ __forceinline__ unsigned short f2bf(float x) {
    unsigned int u = __builtin_bit_cast(unsigned int, x);
    u += 0x7FFFu + ((u >> 16) & 1u);           // RNE (inputs finite)
    return (unsigned short)(u >> 16);
}
__device__ __forceinline__ float bf2f(unsigned short h) {
    unsigned int u = ((unsigned int)h) << 16;
    return __builtin_bit_cast(float, u);
}

// ---------------- W1 -> bf16 B-fragment pre-pack ----------------
__global__ __launch_bounds__(256) void k_packW1(const float* __restrict__ W1,
                                                unsigned short* __restrict__ Bp) {
    int tid = blockIdx.x * 256 + threadIdx.x;
    if (tid >= 8 * 4 * 64) return;
    const int lane = tid & 63, nt = (tid >> 6) & 3, kt = tid >> 8;
    const int col = nt * 16 + (lane & 15);
    const int kb  = kt * 32 + (lane >> 4) * 8;
    unsigned short o[8];
    #pragma unroll
    for (int j = 0; j < 8; ++j) o[j] = f2bf(W1[(kb + j) * HID + col]);
    #pragma unroll
    for (int j = 0; j < 8; ++j) Bp[tid * 8 + j] = o[j];
}

// ---------------- fused: GEMM1 (MFMA) + dual src/dst bucket-count -------------
// r3: odeg chunk-histogram (16x src re-read, 25KB LDS killing occupancy to
// 16.6%) is ELIMINATED — out-degree is obtained by running the same counting
// sort on src (count fused here; placeS below emits nsrcf directly).
// LDS is now 3128B -> GEMM blocks back to VGPR-limited occupancy.
__global__ __launch_bounds__(256) void k_gemm1c(const float* __restrict__ X,
                                                const unsigned short* __restrict__ Bp,
                                                const int* __restrict__ src,
                                                const int* __restrict__ dst,
                                                unsigned short* __restrict__ h1b,
                                                int* __restrict__ gcnt) {
    __shared__ int sh[2 * NBKT];              // [0,NBKT)=dst counts, [NBKT,2*NBKT)=src
    const int bid = blockIdx.x, t = threadIdx.x;

    if (bid >= NB_GEMM) {
        // ---------- partition pass a: per-(block,bucket) src+dst counts ------
        const int cb = bid - NB_GEMM;                 // [0, NBP1)
        for (int j = t; j < 2 * NBKT; j += 256) sh[j] = 0;
        __syncthreads();
        const int e0 = cb * EPB;
        for (int i = t; i < EPB; i += 256) {
            atomicAdd(&sh[dst[e0 + i] >> 8], 1);
            atomicAdd(&sh[NBKT + (src[e0 + i] >> 8)], 1);
        }
        __syncthreads();
        for (int k = t; k < 2 * NBKT; k += 256) gcnt[k * NBP1 + cb] = sh[k];
        return;
    }
    // ---------- gemm1 (unchanged) ----------
    const int lane = t & 63;
    const int wid  = t >> 6;
    const int r0w  = bid * 64 + wid * 16;
    if (r0w >= NN) return;
    const int r  = r0w + (lane & 15);
    const int rc = (r < NN) ? r : (NN - 1);
    const float* xrow = X + (size_t)rc * IN_F + (lane >> 4) * 8;
    const bf16x8* bp  = reinterpret_cast<const bf16x8*>(Bp) + lane;

    f32x4 acc0 = {0.f, 0.f, 0.f, 0.f};
    f32x4 acc1 = {0.f, 0.f, 0.f, 0.f};
    f32x4 acc2 = {0.f, 0.f, 0.f, 0.f};
    f32x4 acc3 = {0.f, 0.f, 0.f, 0.f};

    #pragma unroll
    for (int kt = 0; kt < 8; ++kt) {
        const f32x4 v0 = *reinterpret_cast<const f32x4*>(xrow + kt * 32);
        const f32x4 v1 = *reinterpret_cast<const f32x4*>(xrow + kt * 32 + 4);
        bf16x8 a;
        a[0] = (short)f2bf(v0[0]);
        a[1] = (short)f2bf(v0[1]);
        a[2] = (short)f2bf(v0[2]);
        a[3] = (short)f2bf(v0[3]);
        a[4] = (short)f2bf(v1[0]);
        a[5] = (short)f2bf(v1[1]);
        a[6] = (short)f2bf(v1[2]);
        a[7] = (short)f2bf(v1[3]);
        const bf16x8 b0 = bp[(kt * 4 + 0) * 64];
        const bf16x8 b1 = bp[(kt * 4 + 1) * 64];
        const bf16x8 b2 = bp[(kt * 4 + 2) * 64];
        const bf16x8 b3 = bp[(kt * 4 + 3) * 64];
        acc0 = __builtin_amdgcn_mfma_f32_16x16x32_bf16(a, b0, acc0, 0, 0, 0);
        acc1 = __builtin_amdgcn_mfma_f32_16x16x32_bf16(a, b1, acc1, 0, 0, 0);
        acc2 = __builtin_amdgcn_mfma_f32_16x16x32_bf16(a, b2, acc2, 0, 0, 0);
        acc3 = __builtin_amdgcn_mfma_f32_16x16x32_bf16(a, b3, acc3, 0, 0, 0);
    }

    // C/D layout: col = lane&15, row = (lane>>4)*4 + reg   [m89-verified]
    const int crow = r0w + (lane >> 4) * 4;
    const int ccol = lane & 15;
    #pragma unroll
    for (int rr = 0; rr < 4; ++rr) {
        const int orow = crow + rr;
        if (orow < NN) {
            unsigned short* o = h1b + (size_t)orow * HID + ccol;
            o[0]  = f2bf(acc0[rr]);
            o[16] = f2bf(acc1[rr]);
            o[32] = f2bf(acc2[rr]);
            o[48] = f2bf(acc3[rr]);
        }
    }
}

// ---------------- scan A: per-row total = sum over blocks --------------------
// rows r in [0, 2*NBKT): r<NBKT = dst buckets, r>=NBKT = src buckets
__global__ __launch_bounds__(256) void k_scanA(const int* __restrict__ gcnt,
                                               int* __restrict__ bsum) {
    __shared__ int red[256];
    const int r = blockIdx.x, t = threadIdx.x;
    red[t] = gcnt[r * NBP1 + t];              // NBP1 == 256
    __syncthreads();
    for (int off = 128; off > 0; off >>= 1) {
        if (t < off) red[t] += red[t + off];
        __syncthreads();
    }
    if (t == 0) bsum[r] = red[0];
}

// ---------------- scan B: per-array exclusive scan -> bstart[a][0..NBKT] ------
__global__ __launch_bounds__(512) void k_scanB(const int* __restrict__ bsum,
                                               int* __restrict__ bstart) {
    __shared__ int sa[512], sb[512];
    const int a = blockIdx.x, t = threadIdx.x;       // a in {0,1}
    const int x = (t < NBKT) ? bsum[a * NBKT + t] : 0;
    sa[t] = x;
    __syncthreads();
    int* pin = sa; int* pout = sb;
    for (int off = 1; off < 512; off <<= 1) {
        int v = pin[t];
        if (t >= off) v += pin[t - off];
        pout[t] = v;
        __syncthreads();
        int* tmp = pin; pin = pout; pout = tmp;
    }
    if (t <= NBKT) bstart[a * (NBKT + 1) + t] = pin[t] - x;   // exclusive
}

// ---------------- scan C: per-row exclusive scan -> segment bases (in place) --
__global__ __launch_bounds__(256) void k_scanC(int* __restrict__ gcnt,
                                               const int* __restrict__ bstart) {
    __shared__ int sa[256], sb[256];
    const int r = blockIdx.x, t = threadIdx.x;
    const int a = r / NBKT;                           // bstart row offset: r + a
    const int x = gcnt[r * NBP1 + t];
    sa[t] = x;
    __syncthreads();
    int* pin = sa; int* pout = sb;
    for (int off = 1; off < 256; off <<= 1) {
        int v = pin[t];
        if (t >= off) v += pin[t - off];
        pout[t] = v;
        __syncthreads();
        int* tmp = pin; pin = pout; pout = tmp;
    }
    gcnt[r * NBP1 + t] = bstart[r + a] + pin[t] - x;
}

// ---------------- partition pass b: scatter into dst- AND src-bucket segments -
// pedge[posD] = s | (d&255)<<17  (src < 2^17); psrc[posS] = s&255 (bucket known
// per segment). Segment-local writes -> near-full-line granularity, 0 global atomics.
__global__ __launch_bounds__(256) void k_scatter(const int* __restrict__ src,
                                                 const int* __restrict__ dst,
                                                 const int* __restrict__ gbase,
                                                 int* __restrict__ pedge,
                                                 unsigned char* __restrict__ psrc) {
    __shared__ int cur[2 * NBKT];
    const int b = blockIdx.x, t = threadIdx.x;
    for (int k = t; k < 2 * NBKT; k += 256) cur[k] = gbase[k * NBP1 + b];
    __syncthreads();
    const int e0 = b * EPB;
    for (int i = t; i < EPB; i += 256) {
        const int d = dst[e0 + i], s = src[e0 + i];
        const int posD = atomicAdd(&cur[d >> 8], 1);          // LDS atomic
        pedge[posD] = s | ((d & 255) << 17);
        const int posS = atomicAdd(&cur[NBKT + (s >> 8)], 1); // LDS atomic
        psrc[posS] = (unsigned char)(s & 255);
    }
}

// ---------------- placeD: per-bucket CSR slot assignment (LDS counters) -------
__global__ __launch_bounds__(256) void k_placeD(const int* __restrict__ pedge,
                                                const int* __restrict__ bstart,
                                                int* __restrict__ eidx,
                                                int* __restrict__ ideg) {
    __shared__ int cnt[256];
    const int k = blockIdx.x, t = threadIdx.x;
    cnt[t] = 0;
    __syncthreads();
    const int i0 = bstart[k], i1 = bstart[k + 1];
    for (int i = i0 + t; i < i1; i += 256) {
        const int v  = pedge[i];
        const int s  = v & 0x1FFFF;
        const int lo = v >> 17;
        const int c  = atomicAdd(&cnt[lo], 1);                // LDS atomic
        if (c < CAP) eidx[(size_t)((k << 8) | lo) * CAP + c] = s;
    }
    __syncthreads();
    const int d = (k << 8) | t;
    if (d < NN) ideg[d] = cnt[t];
}

// ---------------- placeS: per-bucket src counting -> nsrcf directly -----------
__global__ __launch_bounds__(256) void k_placeS(const unsigned char* __restrict__ psrc,
                                                const int* __restrict__ bstartS,
                                                float* __restrict__ nsrcf) {
    __shared__ int cnt[256];
    const int k = blockIdx.x, t = threadIdx.x;
    cnt[t] = 0;
    __syncthreads();
    const int i0 = bstartS[k], i1 = bstartS[k + 1];
    for (int i = i0 + t; i < i1; i += 256)
        atomicAdd(&cnt[psrc[i]], 1);                          // LDS atomic
    __syncthreads();
    const int d = (k << 8) | t;
    if (d < NN) nsrcf[d] = rsqrtf(fmaxf((float)cnt[t], 1.f));
}

// ---------------- pre-scale h1b rows by norm_src ------------------------------
__global__ __launch_bounds__(256) void k_scale(const float* __restrict__ nsrcf,
                                               unsigned short* __restrict__ h1b) {
    const int gw = (blockIdx.x * 256 + threadIdx.x) >> 4;   // node
    const int gl = threadIdx.x & 15;                        // lane in group
    if (gw >= NN) return;
    const float ns = nsrcf[gw];
    uint2* row = reinterpret_cast<uint2*>(h1b + (size_t)gw * HID);
    uint2 u = row[gl];
    const unsigned short a0 = (unsigned short)(u.x & 0xffffu);
    const unsigned short a1 = (unsigned short)(u.x >> 16);
    const unsigned short a2 = (unsigned short)(u.y & 0xffffu);
    const unsigned short a3 = (unsigned short)(u.y >> 16);
    u.x = (unsigned)f2bf(bf2f(a0) * ns) | ((unsigned)f2bf(bf2f(a1) * ns) << 16);
    u.y = (unsigned)f2bf(bf2f(a2) * ns) | ((unsigned)f2bf(bf2f(a3) * ns) << 16);
    row[gl] = u;
}

// ---------------- aggregation, 64 feats: hout = ndst*(sum h1_scaled) + b1 ----
__global__ __launch_bounds__(256) void k_agg64(const int* __restrict__ eidx,
                                               const int* __restrict__ ideg,
                                               const unsigned short* __restrict__ h1b,
                                               const float* __restrict__ b1,
                                               float* __restrict__ hout) {
    const int w    = (blockIdx.x * 256 + threadIdx.x) >> 6;
    const int lane = threadIdx.x & 63;
    if (w >= NN) return;
    const int cnt = ideg[w];
    const int m   = cnt < CAP ? cnt : CAP;
    const int* row = eidx + w * CAP;                       // 256B-aligned
    float acc = 0.f;
    int j = 0;
    for (; j + 4 <= m; j += 4) {
        const int4 q = *reinterpret_cast<const int4*>(row + j);
        const float v0 = bf2f(h1b[(size_t)q.x * HID + lane]);
        const float v1 = bf2f(h1b[(size_t)q.y * HID + lane]);
        const float v2 = bf2f(h1b[(size_t)q.z * HID + lane]);
        const float v3 = bf2f(h1b[(size_t)q.w * HID + lane]);
        acc += (v0 + v1) + (v2 + v3);
    }
    for (; j < m; ++j)
        acc += bf2f(h1b[(size_t)row[j] * HID + lane]);
    const float nd = rsqrtf(fmaxf((float)cnt, 1.f));
    hout[(size_t)w * HID + lane] = fmaf(acc, nd, b1[lane]);
}

// ---------------- layer 2 GEMM: xwb[n][c] = bf16( (relu(h[n]) @ W2)[c] * nsrc[n] )
__global__ __launch_bounds__(256) void k_gemm2(const float* __restrict__ h,
                                               const float* __restrict__ W2,
                                               const float* __restrict__ nsrcf,
                                               unsigned short* __restrict__ xwb) {
    __shared__ float lw[HID * NC];                 // 10 KiB
    for (int i = threadIdx.x; i < HID * NC; i += 256) lw[i] = W2[i];
    __syncthreads();
    int idx = blockIdx.x * 256 + threadIdx.x;
    if (idx >= NN * NC) return;
    int nrow = idx / NC, c = idx - nrow * NC;
    const float4* hr = reinterpret_cast<const float4*>(h + (size_t)nrow * HID);
    float acc = 0.f;
    #pragma unroll
    for (int k4 = 0; k4 < HID / 4; ++k4) {
        float4 v = hr[k4];
        int k = k4 * 4;
        acc = fmaf(fmaxf(v.x, 0.f), lw[(k + 0) * NC + c], acc);
        acc = fmaf(fmaxf(v.y, 0.f), lw[(k + 1) * NC + c], acc);
        acc = fmaf(fmaxf(v.z, 0.f), lw[(k + 2) * NC + c], acc);
        acc = fmaf(fmaxf(v.w, 0.f), lw[(k + 3) * NC + c], acc);
    }
    xwb[idx] = f2bf(acc * nsrcf[nrow]);
}

// ---------------- aggregation, 40 feats: out = ndst*(sum xwb) + b2 -----------
__global__ __launch_bounds__(256) void k_agg40(const int* __restrict__ eidx,
                                               const int* __restrict__ ideg,
                                               const unsigned short* __restrict__ xwb,
                                               const float* __restrict__ b2,
                                               float* __restrict__ out) {
    const int w    = (blockIdx.x * 256 + threadIdx.x) >> 6;
    const int lane = threadIdx.x & 63;
    if (w >= NN || lane >= NC) return;
    const int cnt = ideg[w];
    const int m   = cnt < CAP ? cnt : CAP;
    const int* row = eidx + w * CAP;
    float acc = 0.f;
    int j = 0;
    for (; j + 4 <= m; j += 4) {
        const int4 q = *reinterpret_cast<const int4*>(row + j);
        const float v0 = bf2f(xwb[(size_t)q.x * NC + lane]);
        const float v1 = bf2f(xwb[(size_t)q.y * NC + lane]);
        const float v2 = bf2f(xwb[(size_t)q.z * NC + lane]);
        const float v3 = bf2f(xwb[(size_t)q.w * NC + lane]);
        acc += (v0 + v1) + (v2 + v3);
    }
    for (; j < m; ++j) acc += bf2f(xwb[(size_t)row[j] * NC + lane]);
    const float nd = rsqrtf(fmaxf((float)cnt, 1.f));
    out[(size_t)w * NC + lane] = fmaf(acc, nd, b2[lane]);
}

extern "C" void kernel_launch(void* const* d_in, const int* in_sizes, int n_in,
                              void* d_out, int out_size, void* d_ws, size_t ws_size,
                              hipStream_t stream) {
    const float* X   = (const float*)d_in[0];
    const int*   src = (const int*)d_in[1];
    const int*   dst = (const int*)d_in[2];
    const float* W1  = (const float*)d_in[3];
    const float* b1  = (const float*)d_in[4];
    const float* W2  = (const float*)d_in[5];
    const float* b2  = (const float*)d_in[6];

    float* out  = (float*)d_out;
    float* xout = out;                          // [NN*NC] final layer-2 output
    float* hout = out + (size_t)NN * NC;        // [NN*HID] layer-1 output h

    // ---- scratch living in d_out (liveness-checked):
    // gcnt/bsum/bstart in xout region (<1MB of 16MB): dead before k_agg40 writes xout.
    // pedge+psrc in hout region (8MB of 25.6MB): dead before k_agg64 writes hout.
    int* gcnt   = (int*)xout;                   // [2*NBKT*NBP1] counts -> bases (in-place)
    int* bsum   = gcnt + 2 * NBKT * NBP1;       // [2*NBKT]
    int* bstart = bsum + 2 * NBKT;              // [2*(NBKT+1)]
    int* pedge  = (int*)hout;                   // [NE] packed (src | dlow<<17)
    unsigned char* psrc = (unsigned char*)(pedge + NE);   // [NE] low byte of src

    // ---- workspace layout ----
    char* ws = (char*)d_ws;
    int* ideg  = (int*)ws;                            ws += sizeof(int) * NN;
    int* eidx  = (int*)ws;                            ws += sizeof(int) * (size_t)NN * CAP;
    unsigned short* Bp  = (unsigned short*)ws;        ws += sizeof(unsigned short) * 8 * 4 * 64 * 8;
    float* nsrcf = (float*)ws;                        ws += sizeof(float) * NN;
    unsigned short* h1b = (unsigned short*)ws;        // [NN*HID] bf16, 12.8 MB
    unsigned short* xwb = h1b;                        // reuse: h1b dead after agg64

    // no memsets: every consumed location is written each launch
    k_packW1 <<<8, 256, 0, stream>>>(W1, Bp);
    k_gemm1c <<<NB_GEMM + NBP1, 256, 0, stream>>>(X, Bp, src, dst, h1b, gcnt);
    k_scanA  <<<2 * NBKT, 256, 0, stream>>>(gcnt, bsum);
    k_scanB  <<<2, 512, 0, stream>>>(bsum, bstart);
    k_scanC  <<<2 * NBKT, 256, 0, stream>>>(gcnt, bstart);
    k_scatter<<<NBP1, 256, 0, stream>>>(src, dst, gcnt, pedge, psrc);
    k_placeD <<<NBKT, 256, 0, stream>>>(pedge, bstart, eidx, ideg);
    k_placeS <<<NBKT, 256, 0, stream>>>(psrc, bstart + (NBKT + 1), nsrcf);
    k_scale  <<<(NN * 16 + 255) / 256, 256, 0, stream>>>(nsrcf, h1b);
    k_agg64  <<<(NN * 64 + 255) / 256, 256, 0, stream>>>(eidx, ideg, h1b, b1, hout);
    k_gemm2  <<<(NN * NC + 255) / 256, 256, 0, stream>>>(hout, W2, nsrcf, xwb);
    k_agg40  <<<(NN * 64 + 255) / 256, 256, 0, stream>>>(eidx, ideg, xwb, b2, xout);
}

// Round 4
// 229.076 us; speedup vs baseline: 1.6261x; 1.1912x over previous
//
#include <hip/hip_runtime.h>
#include <hip/hip_bf16.h>

#define NN       100000    // nodes
#define NE       1600000   // edges
#define IN_F     256
#define HID      64
#define NC       40
#define CAP      64        // fixed CSR slots/node; P(in-deg > 64) ~ 1e-19 for Poisson(16)
#define NBKT     391       // node buckets: bucket = id >> 8 (256 nodes each)
#define NBP1     256       // partition blocks; EPB edges each
#define EPB      6250      // NE / NBP1 (exact)
#define NB_GEMM  1563      // ceil(NN/64)

typedef __attribute__((ext_vector_type(8))) short bf16x8;
typedef __attribute__((ext_vector_type(4))) float f32x4;

__device__ __forceinline__ unsigned short f2bf(float x) {
    unsigned int u = __builtin_bit_cast(unsigned int, x);
    u += 0x7FFFu + ((u >> 16) & 1u);           // RNE (inputs finite)
    return (unsigned short)(u >> 16);
}
__device__ __forceinline__ float bf2f(unsigned short h) {
    unsigned int u = ((unsigned int)h) << 16;
    return __builtin_bit_cast(float, u);
}

// ---------------- W1 -> bf16 B-fragment pre-pack ----------------
__global__ __launch_bounds__(256) void k_packW1(const float* __restrict__ W1,
                                                unsigned short* __restrict__ Bp) {
    int tid = blockIdx.x * 256 + threadIdx.x;
    if (tid >= 8 * 4 * 64) return;
    const int lane = tid & 63, nt = (tid >> 6) & 3, kt = tid >> 8;
    const int col = nt * 16 + (lane & 15);
    const int kb  = kt * 32 + (lane >> 4) * 8;
    unsigned short o[8];
    #pragma unroll
    for (int j = 0; j < 8; ++j) o[j] = f2bf(W1[(kb + j) * HID + col]);
    #pragma unroll
    for (int j = 0; j < 8; ++j) Bp[tid * 8 + j] = o[j];
}

// ---------------- fused: GEMM1 (MFMA) + dual src/dst bucket-count -------------
__global__ __launch_bounds__(256) void k_gemm1c(const float* __restrict__ X,
                                                const unsigned short* __restrict__ Bp,
                                                const int* __restrict__ src,
                                                const int* __restrict__ dst,
                                                unsigned short* __restrict__ h1b,
                                                int* __restrict__ gcnt) {
    __shared__ int sh[2 * NBKT];              // [0,NBKT)=dst counts, [NBKT,2*NBKT)=src
    const int bid = blockIdx.x, t = threadIdx.x;

    if (bid >= NB_GEMM) {
        // ---------- partition pass a: per-(block,bucket) src+dst counts ------
        const int cb = bid - NB_GEMM;                 // [0, NBP1)
        for (int j = t; j < 2 * NBKT; j += 256) sh[j] = 0;
        __syncthreads();
        const int e0 = cb * EPB;
        for (int i = t; i < EPB; i += 256) {
            atomicAdd(&sh[dst[e0 + i] >> 8], 1);
            atomicAdd(&sh[NBKT + (src[e0 + i] >> 8)], 1);
        }
        __syncthreads();
        for (int k = t; k < 2 * NBKT; k += 256) gcnt[k * NBP1 + cb] = sh[k];
        return;
    }
    // ---------- gemm1 ----------
    const int lane = t & 63;
    const int wid  = t >> 6;
    const int r0w  = bid * 64 + wid * 16;
    if (r0w >= NN) return;
    const int r  = r0w + (lane & 15);
    const int rc = (r < NN) ? r : (NN - 1);
    const float* xrow = X + (size_t)rc * IN_F + (lane >> 4) * 8;
    const bf16x8* bp  = reinterpret_cast<const bf16x8*>(Bp) + lane;

    f32x4 acc0 = {0.f, 0.f, 0.f, 0.f};
    f32x4 acc1 = {0.f, 0.f, 0.f, 0.f};
    f32x4 acc2 = {0.f, 0.f, 0.f, 0.f};
    f32x4 acc3 = {0.f, 0.f, 0.f, 0.f};

    #pragma unroll
    for (int kt = 0; kt < 8; ++kt) {
        const f32x4 v0 = *reinterpret_cast<const f32x4*>(xrow + kt * 32);
        const f32x4 v1 = *reinterpret_cast<const f32x4*>(xrow + kt * 32 + 4);
        bf16x8 a;
        a[0] = (short)f2bf(v0[0]);
        a[1] = (short)f2bf(v0[1]);
        a[2] = (short)f2bf(v0[2]);
        a[3] = (short)f2bf(v0[3]);
        a[4] = (short)f2bf(v1[0]);
        a[5] = (short)f2bf(v1[1]);
        a[6] = (short)f2bf(v1[2]);
        a[7] = (short)f2bf(v1[3]);
        const bf16x8 b0 = bp[(kt * 4 + 0) * 64];
        const bf16x8 b1 = bp[(kt * 4 + 1) * 64];
        const bf16x8 b2 = bp[(kt * 4 + 2) * 64];
        const bf16x8 b3 = bp[(kt * 4 + 3) * 64];
        acc0 = __builtin_amdgcn_mfma_f32_16x16x32_bf16(a, b0, acc0, 0, 0, 0);
        acc1 = __builtin_amdgcn_mfma_f32_16x16x32_bf16(a, b1, acc1, 0, 0, 0);
        acc2 = __builtin_amdgcn_mfma_f32_16x16x32_bf16(a, b2, acc2, 0, 0, 0);
        acc3 = __builtin_amdgcn_mfma_f32_16x16x32_bf16(a, b3, acc3, 0, 0, 0);
    }

    // C/D layout: col = lane&15, row = (lane>>4)*4 + reg   [m89-verified]
    const int crow = r0w + (lane >> 4) * 4;
    const int ccol = lane & 15;
    #pragma unroll
    for (int rr = 0; rr < 4; ++rr) {
        const int orow = crow + rr;
        if (orow < NN) {
            unsigned short* o = h1b + (size_t)orow * HID + ccol;
            o[0]  = f2bf(acc0[rr]);
            o[16] = f2bf(acc1[rr]);
            o[32] = f2bf(acc2[rr]);
            o[48] = f2bf(acc3[rr]);
        }
    }
}

// ---------------- scan A: per-row total = sum over blocks --------------------
__global__ __launch_bounds__(256) void k_scanA(const int* __restrict__ gcnt,
                                               int* __restrict__ bsum) {
    __shared__ int red[256];
    const int r = blockIdx.x, t = threadIdx.x;
    red[t] = gcnt[r * NBP1 + t];              // NBP1 == 256
    __syncthreads();
    for (int off = 128; off > 0; off >>= 1) {
        if (t < off) red[t] += red[t + off];
        __syncthreads();
    }
    if (t == 0) bsum[r] = red[0];
}

// ---------------- scan B: per-array exclusive scan -> bstart[a][0..NBKT] ------
__global__ __launch_bounds__(512) void k_scanB(const int* __restrict__ bsum,
                                               int* __restrict__ bstart) {
    __shared__ int sa[512], sb[512];
    const int a = blockIdx.x, t = threadIdx.x;       // a in {0,1}
    const int x = (t < NBKT) ? bsum[a * NBKT + t] : 0;
    sa[t] = x;
    __syncthreads();
    int* pin = sa; int* pout = sb;
    for (int off = 1; off < 512; off <<= 1) {
        int v = pin[t];
        if (t >= off) v += pin[t - off];
        pout[t] = v;
        __syncthreads();
        int* tmp = pin; pin = pout; pout = tmp;
    }
    if (t <= NBKT) bstart[a * (NBKT + 1) + t] = pin[t] - x;   // exclusive
}

// ---------------- scan C: per-row exclusive scan -> segment bases (in place) --
__global__ __launch_bounds__(256) void k_scanC(int* __restrict__ gcnt,
                                               const int* __restrict__ bstart) {
    __shared__ int sa[256], sb[256];
    const int r = blockIdx.x, t = threadIdx.x;
    const int a = r / NBKT;                           // bstart row offset: r + a
    const int x = gcnt[r * NBP1 + t];
    sa[t] = x;
    __syncthreads();
    int* pin = sa; int* pout = sb;
    for (int off = 1; off < 256; off <<= 1) {
        int v = pin[t];
        if (t >= off) v += pin[t - off];
        pout[t] = v;
        __syncthreads();
        int* tmp = pin; pin = pout; pout = tmp;
    }
    gcnt[r * NBP1 + t] = bstart[r + a] + pin[t] - x;
}

// ---------------- partition pass b: scatter into dst- AND src-bucket segments -
__global__ __launch_bounds__(256) void k_scatter(const int* __restrict__ src,
                                                 const int* __restrict__ dst,
                                                 const int* __restrict__ gbase,
                                                 int* __restrict__ pedge,
                                                 unsigned char* __restrict__ psrc) {
    __shared__ int cur[2 * NBKT];
    const int b = blockIdx.x, t = threadIdx.x;
    for (int k = t; k < 2 * NBKT; k += 256) cur[k] = gbase[k * NBP1 + b];
    __syncthreads();
    const int e0 = b * EPB;
    for (int i = t; i < EPB; i += 256) {
        const int d = dst[e0 + i], s = src[e0 + i];
        const int posD = atomicAdd(&cur[d >> 8], 1);          // LDS atomic
        pedge[posD] = s | ((d & 255) << 17);
        const int posS = atomicAdd(&cur[NBKT + (s >> 8)], 1); // LDS atomic
        psrc[posS] = (unsigned char)(s & 255);
    }
}

// ---------------- place (merged D+S): CSR slots + ideg | src counts -> nsrcf --
__global__ __launch_bounds__(256) void k_place(const int* __restrict__ pedge,
                                               const unsigned char* __restrict__ psrc,
                                               const int* __restrict__ bstart,
                                               int* __restrict__ eidx,
                                               int* __restrict__ ideg,
                                               float* __restrict__ nsrcf) {
    __shared__ int cnt[256];
    const int kk = blockIdx.x, t = threadIdx.x;
    cnt[t] = 0;
    __syncthreads();
    if (kk < NBKT) {
        const int k  = kk;
        const int i0 = bstart[k], i1 = bstart[k + 1];
        for (int i = i0 + t; i < i1; i += 256) {
            const int v  = pedge[i];
            const int s  = v & 0x1FFFF;
            const int lo = v >> 17;
            const int c  = atomicAdd(&cnt[lo], 1);            // LDS atomic
            if (c < CAP) eidx[(size_t)((k << 8) | lo) * CAP + c] = s;
        }
        __syncthreads();
        const int d = (k << 8) | t;
        if (d < NN) ideg[d] = cnt[t];
    } else {
        const int k  = kk - NBKT;
        const int* bs = bstart + (NBKT + 1);
        const int i0 = bs[k], i1 = bs[k + 1];
        for (int i = i0 + t; i < i1; i += 256)
            atomicAdd(&cnt[psrc[i]], 1);                      // LDS atomic
        __syncthreads();
        const int d = (k << 8) | t;
        if (d < NN) nsrcf[d] = rsqrtf(fmaxf((float)cnt[t], 1.f));
    }
}

// ---------------- aggregation, 64 feats ---------------------------------------
// r4: readlane-indexed gather. Slot row loaded ONCE (256B coalesced) into a
// register; neighbor ids extracted with v_readlane -> SGPR, so gathers are
// saddr-form (no per-lane 64b address math) and there is NO dependent index
// load in the loop. nsrc applied per neighbor via uniform scalar load
// (k_scale pass deleted). Unroll 8 -> 8 outstanding gathers/wave.
__global__ __launch_bounds__(256) void k_agg64(const int* __restrict__ eidx,
                                               const int* __restrict__ ideg,
                                               const float* __restrict__ nsrcf,
                                               const unsigned short* __restrict__ h1b,
                                               const float* __restrict__ b1,
                                               float* __restrict__ hout) {
    const int w    = (blockIdx.x * 256 + threadIdx.x) >> 6;
    const int lane = threadIdx.x & 63;
    if (w >= NN) return;
    const int cnt  = ideg[w];
    const int m    = cnt < CAP ? cnt : CAP;
    const int idxv = eidx[(size_t)w * CAP + lane];   // slots >= m hold garbage: never read
    float acc = 0.f;
    int j = 0;
    for (; j + 8 <= m; j += 8) {
        int s[8];
        #pragma unroll
        for (int u = 0; u < 8; ++u) s[u] = __builtin_amdgcn_readlane(idxv, j + u);
        #pragma unroll
        for (int u = 0; u < 8; ++u)
            acc = fmaf(bf2f(h1b[(size_t)s[u] * HID + lane]), nsrcf[s[u]], acc);
    }
    for (; j < m; ++j) {
        const int s = __builtin_amdgcn_readlane(idxv, j);
        acc = fmaf(bf2f(h1b[(size_t)s * HID + lane]), nsrcf[s], acc);
    }
    const float nd = rsqrtf(fmaxf((float)cnt, 1.f));
    hout[(size_t)w * HID + lane] = fmaf(acc, nd, b1[lane]);
}

// ---------------- layer 2 GEMM: xwb[n][c] = bf16( (relu(h[n]) @ W2)[c] * nsrc[n] )
__global__ __launch_bounds__(256) void k_gemm2(const float* __restrict__ h,
                                               const float* __restrict__ W2,
                                               const float* __restrict__ nsrcf,
                                               unsigned short* __restrict__ xwb) {
    __shared__ float lw[HID * NC];                 // 10 KiB
    for (int i = threadIdx.x; i < HID * NC; i += 256) lw[i] = W2[i];
    __syncthreads();
    int idx = blockIdx.x * 256 + threadIdx.x;
    if (idx >= NN * NC) return;
    int nrow = idx / NC, c = idx - nrow * NC;
    const float4* hr = reinterpret_cast<const float4*>(h + (size_t)nrow * HID);
    float acc = 0.f;
    #pragma unroll
    for (int k4 = 0; k4 < HID / 4; ++k4) {
        float4 v = hr[k4];
        int k = k4 * 4;
        acc = fmaf(fmaxf(v.x, 0.f), lw[(k + 0) * NC + c], acc);
        acc = fmaf(fmaxf(v.y, 0.f), lw[(k + 1) * NC + c], acc);
        acc = fmaf(fmaxf(v.z, 0.f), lw[(k + 2) * NC + c], acc);
        acc = fmaf(fmaxf(v.w, 0.f), lw[(k + 3) * NC + c], acc);
    }
    xwb[idx] = f2bf(acc * nsrcf[nrow]);
}

// ---------------- aggregation, 40 feats (readlane gather, lane-clamped) -------
__global__ __launch_bounds__(256) void k_agg40(const int* __restrict__ eidx,
                                               const int* __restrict__ ideg,
                                               const unsigned short* __restrict__ xwb,
                                               const float* __restrict__ b2,
                                               float* __restrict__ out) {
    const int w    = (blockIdx.x * 256 + threadIdx.x) >> 6;
    const int lane = threadIdx.x & 63;
    if (w >= NN) return;
    const int cnt  = ideg[w];
    const int m    = cnt < CAP ? cnt : CAP;
    const int idxv = eidx[(size_t)w * CAP + lane];
    const int fl   = lane < NC ? lane : 0;    // clamp: dup loads stay inside row line
    float acc = 0.f;
    int j = 0;
    for (; j + 8 <= m; j += 8) {
        int s[8];
        #pragma unroll
        for (int u = 0; u < 8; ++u) s[u] = __builtin_amdgcn_readlane(idxv, j + u);
        #pragma unroll
        for (int u = 0; u < 8; ++u)
            acc += bf2f(xwb[(size_t)s[u] * NC + fl]);
    }
    for (; j < m; ++j) {
        const int s = __builtin_amdgcn_readlane(idxv, j);
        acc += bf2f(xwb[(size_t)s * NC + fl]);
    }
    if (lane < NC) {
        const float nd = rsqrtf(fmaxf((float)cnt, 1.f));
        out[(size_t)w * NC + lane] = fmaf(acc, nd, b2[lane]);
    }
}

extern "C" void kernel_launch(void* const* d_in, const int* in_sizes, int n_in,
                              void* d_out, int out_size, void* d_ws, size_t ws_size,
                              hipStream_t stream) {
    const float* X   = (const float*)d_in[0];
    const int*   src = (const int*)d_in[1];
    const int*   dst = (const int*)d_in[2];
    const float* W1  = (const float*)d_in[3];
    const float* b1  = (const float*)d_in[4];
    const float* W2  = (const float*)d_in[5];
    const float* b2  = (const float*)d_in[6];

    float* out  = (float*)d_out;
    float* xout = out;                          // [NN*NC] final layer-2 output
    float* hout = out + (size_t)NN * NC;        // [NN*HID] layer-1 output h

    // ---- scratch living in d_out (liveness-checked):
    // gcnt/bsum/bstart in xout region (<1MB of 16MB): dead before k_agg40 writes xout.
    // pedge+psrc in hout region (8MB of 25.6MB): dead before k_agg64 writes hout.
    int* gcnt   = (int*)xout;                   // [2*NBKT*NBP1] counts -> bases (in-place)
    int* bsum   = gcnt + 2 * NBKT * NBP1;       // [2*NBKT]
    int* bstart = bsum + 2 * NBKT;              // [2*(NBKT+1)]
    int* pedge  = (int*)hout;                   // [NE] packed (src | dlow<<17)
    unsigned char* psrc = (unsigned char*)(pedge + NE);   // [NE] low byte of src

    // ---- workspace layout ----
    char* ws = (char*)d_ws;
    int* ideg  = (int*)ws;                            ws += sizeof(int) * NN;
    int* eidx  = (int*)ws;                            ws += sizeof(int) * (size_t)NN * CAP;
    unsigned short* Bp  = (unsigned short*)ws;        ws += sizeof(unsigned short) * 8 * 4 * 64 * 8;
    float* nsrcf = (float*)ws;                        ws += sizeof(float) * NN;
    unsigned short* h1b = (unsigned short*)ws;        // [NN*HID] bf16, 12.8 MB
    unsigned short* xwb = h1b;                        // reuse: h1b dead after agg64

    // no memsets: every consumed location is written each launch
    k_packW1 <<<8, 256, 0, stream>>>(W1, Bp);
    k_gemm1c <<<NB_GEMM + NBP1, 256, 0, stream>>>(X, Bp, src, dst, h1b, gcnt);
    k_scanA  <<<2 * NBKT, 256, 0, stream>>>(gcnt, bsum);
    k_scanB  <<<2, 512, 0, stream>>>(bsum, bstart);
    k_scanC  <<<2 * NBKT, 256, 0, stream>>>(gcnt, bstart);
    k_scatter<<<NBP1, 256, 0, stream>>>(src, dst, gcnt, pedge, psrc);
    k_place  <<<2 * NBKT, 256, 0, stream>>>(pedge, psrc, bstart, eidx, ideg, nsrcf);
    k_agg64  <<<(NN * 64 + 255) / 256, 256, 0, stream>>>(eidx, ideg, nsrcf, h1b, b1, hout);
    k_gemm2  <<<(NN * NC + 255) / 256, 256, 0, stream>>>(hout, W2, nsrcf, xwb);
    k_agg40  <<<(NN * 64 + 255) / 256, 256, 0, stream>>>(eidx, ideg, xwb, b2, xout);
}